// Round 13
// baseline (237.016 us; speedup 1.0000x reference)
//
#include <hip/hip_runtime.h>

#define N_NODES 50000
#define N_EDGES 1600000
#define D 48

#define NB  256             // grid blocks == prep chunks (<=512 co-resident capacity, no deadlock)
#define TPB 1024
#define EPB 6272            // NB*EPB = 1,605,632 >= N_EDGES
#define NPB_D 64
#define NBIN_D 782          // ceil(50000/64)
#define NPB_S 256
#define NBIN_S 196          // ceil(50000/256)

#define EMAX 3072           // per-dst-bin edge cap (mean 2048, sigma ~45)
#define HS 52               // h/W LDS stride (16B-aligned, bank-spread; proven R10)

// ---------- workspace layout (bytes), total ~8.73 MB ----------
#define RECD_OFF  0          // u32[NB*EPB] block-major (src<<6)|dlocal
#define SRCB_OFF  6422528    // u8 [NB*EPB] block-major src&255
#define CI_OFF    8028160    // f32[50000]
#define OFFLD_OFF 8228160    // u16[NB][NBIN_D+1]
#define OFFLS_OFF 8629056    // u16[NB][NBIN_S+1]
#define BAR_OFF   8729920    // int[2] barrier counter (memset to 0 each call)

__device__ __forceinline__ void gridbar(int* bar, int target) {
    __syncthreads();
    if (threadIdx.x == 0) {
        __threadfence();                      // release: publish this block's writes
        atomicAdd(bar, 1);                    // device-scope by default
        while (atomicAdd(bar, 0) < target)
            __builtin_amdgcn_s_sleep(4);
        __threadfence();                      // acquire: invalidate stale caches
    }
    __syncthreads();
}

__global__ __launch_bounds__(TPB) void k_fused(
    const int* __restrict__ src, const int* __restrict__ dst,
    const float* __restrict__ feat, const float* __restrict__ W,
    const float* __restrict__ b, float* __restrict__ out,
    unsigned int* __restrict__ rec, unsigned char* __restrict__ srcb,
    float* __restrict__ ci, unsigned short* __restrict__ offld,
    unsigned short* __restrict__ offls, int* bar) {

    __shared__ union U_t {
        struct {
            unsigned int bufd[EPB];           // 25088
            int scan[TPB];                    // 4096
            int cd[NBIN_D];                   // 3128
            int cs[NBIN_S];                   // 784
            unsigned char bufs[EPB];          // 6272
        } p1;
        struct { int cnt[NPB_S]; } p2;
        struct {
            int   craw[EMAX];                 // 12288
            int   colb[EMAX];                 // 12288
            float hl[NPB_D * HS];             // 13312 (offset 24576, 16-aligned)
            float Wl[D * HS];                 // 9984
            float bl[D];
            int   ideg[NPB_D];
            int   off[NPB_D];
            int   cur[NPB_D];
            int   runpos[NB];
            int   runoff[NB + 1];
            int   rs[NB];
        } p3;
    } U;
    static_assert(sizeof(U.p1) < 160 * 1024 && sizeof(U.p3) < 160 * 1024, "lds");

    int tid = threadIdx.x, blk = blockIdx.x;

    // ================= Phase 1: per-block two-key binning =================
    {
        int base = blk * EPB;
        int sv[7], dv[7];
        bool ok[7];
        #pragma unroll
        for (int k = 0; k < 7; ++k) {
            int j = tid + k * TPB;
            int e = base + j;
            ok[k] = (j < EPB) && (e < N_EDGES);
            sv[k] = ok[k] ? src[e] : 0;
            dv[k] = ok[k] ? dst[e] : 0;
        }
        for (int i = tid; i < NBIN_D; i += TPB) U.p1.cd[i] = 0;
        for (int i = tid; i < NBIN_S; i += TPB) U.p1.cs[i] = 0;
        __syncthreads();
        #pragma unroll
        for (int k = 0; k < 7; ++k) {
            if (ok[k]) {
                atomicAdd(&U.p1.cd[dv[k] >> 6], 1);
                atomicAdd(&U.p1.cs[sv[k] >> 8], 1);
            }
        }
        __syncthreads();

        // fused scan over [cd | cs] (782 + 196 = 978 <= 1024)
        int own = 0;
        if (tid < NBIN_D) own = U.p1.cd[tid];
        else if (tid < NBIN_D + NBIN_S) own = U.p1.cs[tid - NBIN_D];
        U.p1.scan[tid] = own;
        __syncthreads();
        for (int o = 1; o < TPB; o <<= 1) {
            int x = (tid >= o) ? U.p1.scan[tid - o] : 0;
            __syncthreads();
            U.p1.scan[tid] += x;
            __syncthreads();
        }
        int incl = U.p1.scan[tid];
        int cdt = U.p1.scan[NBIN_D - 1];
        __syncthreads();

        if (tid < NBIN_D) {
            int ex = incl - own;
            offld[blk * (NBIN_D + 1) + tid] = (unsigned short)ex;
            U.p1.cd[tid] = ex;
            if (tid == NBIN_D - 1) offld[blk * (NBIN_D + 1) + NBIN_D] = (unsigned short)incl;
        } else if (tid < NBIN_D + NBIN_S) {
            int t = tid - NBIN_D;
            int ex = (incl - cdt) - own;
            offls[blk * (NBIN_S + 1) + t] = (unsigned short)ex;
            U.p1.cs[t] = ex;
            if (t == NBIN_S - 1) offls[blk * (NBIN_S + 1) + NBIN_S] = (unsigned short)(incl - cdt);
        }
        __syncthreads();

        #pragma unroll
        for (int k = 0; k < 7; ++k) {
            if (ok[k]) {
                int s = sv[k], d = dv[k];
                int pd = atomicAdd(&U.p1.cd[d >> 6], 1);
                U.p1.bufd[pd] = ((unsigned int)s << 6) | (unsigned int)(d & 63);
                int ps = atomicAdd(&U.p1.cs[s >> 8], 1);
                U.p1.bufs[ps] = (unsigned char)s;
            }
        }
        __syncthreads();

        int4* ro = (int4*)(rec + base);
        const int4* bi = (const int4*)U.p1.bufd;
        for (int i = tid; i < EPB / 4; i += TPB) ro[i] = bi[i];
        unsigned int* so = (unsigned int*)(srcb + base);
        const unsigned int* bs = (const unsigned int*)U.p1.bufs;
        for (int i = tid; i < EPB / 4; i += TPB) so[i] = bs[i];
    }

    gridbar(bar, NB);

    // ================= Phase 2: out-degree -> ci (blocks 0..195) =================
    if (blk < NBIN_S) {
        int sb = blk;
        if (tid < NPB_S) U.p2.cnt[tid] = 0;
        __syncthreads();
        int wave = tid >> 6, lane = tid & 63;
        for (int p = wave; p < NB; p += 16) {
            int o0 = offls[p * (NBIN_S + 1) + sb];
            int o1 = offls[p * (NBIN_S + 1) + sb + 1];
            for (int j = o0 + lane; j < o1; j += 64)
                atomicAdd(&U.p2.cnt[srcb[p * EPB + j]], 1);
        }
        __syncthreads();
        if (tid < NPB_S) {
            int n = sb * NPB_S + tid;
            if (n < N_NODES) ci[n] = rsqrtf(fmaxf((float)U.p2.cnt[tid], 1.0f));
        }
    }

    gridbar(bar, 2 * NB);

    // ================= Phase 3: per-bin CSR + gather + GEMM =================
    for (int i = tid; i < D * D; i += TPB) U.p3.Wl[(i / D) * HS + (i % D)] = W[i];
    if (tid < D) U.p3.bl[tid] = b[tid];

    int wave = tid >> 6, lane = tid & 63;
    int eslot = lane / 12;                    // 0..5 (slot 5 inactive)
    int d4 = lane - eslot * 12;               // 0..11
    bool lane_ok = (lane < 60);
    const float4* feat4 = (const float4*)feat;

    for (int bin = blk; bin < NBIN_D; bin += NB) {
        __syncthreads();                      // previous bin fully done (+ Wl/bl on first iter)
        if (tid < NPB_D) { U.p3.ideg[tid] = 0; U.p3.cur[tid] = 0; }
        int rl = 0;
        if (tid < NB) {
            int o0 = offld[tid * (NBIN_D + 1) + bin];
            int o1 = offld[tid * (NBIN_D + 1) + bin + 1];
            rl = o1 - o0;
            U.p3.runpos[tid] = tid * EPB + o0;
            U.p3.rs[tid] = rl;
        }
        __syncthreads();
        for (int o = 1; o < NB; o <<= 1) {
            int x = 0;
            if (tid < NB && tid >= o) x = U.p3.rs[tid - o];
            __syncthreads();
            if (tid < NB) U.p3.rs[tid] += x;
            __syncthreads();
        }
        if (tid < NB) U.p3.runoff[tid] = U.p3.rs[tid] - rl;
        if (tid == 0) U.p3.runoff[NB] = U.p3.rs[NB - 1];
        __syncthreads();

        // copy runs into craw (4 threads per run) + in-degree histogram
        {
            int r = tid >> 2, sub = tid & 3;
            int rbase = U.p3.runoff[r];
            int rlen = U.p3.runoff[r + 1] - rbase;
            int gpos = U.p3.runpos[r];
            for (int j = sub; j < rlen; j += 4) {
                int idx = rbase + j;
                if (idx < EMAX) {
                    int v = (int)rec[gpos + j];
                    U.p3.craw[idx] = v;
                    atomicAdd(&U.p3.ideg[v & 63], 1);
                }
            }
        }
        __syncthreads();
        int cnt = U.p3.runoff[NB];
        if (cnt > EMAX) cnt = EMAX;

        if (tid < NPB_D) {
            int v = U.p3.ideg[tid];
            int incl = v;
            for (int o = 1; o < 64; o <<= 1) {
                int u = __shfl_up(incl, o);
                if (tid >= o) incl += u;
            }
            U.p3.off[tid] = incl - v;
        }
        __syncthreads();
        for (int j = tid; j < cnt; j += TPB) {
            int r = U.p3.craw[j];
            int dl = r & 63;
            int p = atomicAdd(&U.p3.cur[dl], 1);
            U.p3.colb[U.p3.off[dl] + p] = r >> 6;
        }
        __syncthreads();

        // ---- Phase B: ILP-4 float4-lane gather (4 nodes per wave, interleaved) ----
        int nl0 = wave * 4;
        int degq[4], cbq[4];
        float4 acc[4];
        #pragma unroll
        for (int q = 0; q < 4; ++q) {
            degq[q] = U.p3.ideg[nl0 + q];
            cbq[q] = U.p3.off[nl0 + q];
            acc[q] = make_float4(0.0f, 0.0f, 0.0f, 0.0f);
        }
        int maxdeg = max(max(degq[0], degq[1]), max(degq[2], degq[3]));
        for (int c0 = 0; c0 < maxdeg; c0 += 60) {
            int colv[4]; float civ[4]; int jnq[4];
            #pragma unroll
            for (int q = 0; q < 4; ++q) {
                int jn = degq[q] - c0;
                jnq[q] = jn < 60 ? jn : 60;
                colv[q] = (lane < jnq[q]) ? U.p3.colb[cbq[q] + c0 + lane] : 0;
                civ[q]  = (lane < jnq[q]) ? ci[colv[q]] : 0.0f;
            }
            int rem = maxdeg - c0;
            int maxjn = rem < 60 ? rem : 60;
            for (int i = 0; i < maxjn; i += 5) {
                int ei = i + eslot;
                // shfls UNCONDITIONAL (full exec): ds_bpermute from an
                // exec-masked-off source lane is undefined — R12's bug.
                int sq[4]; float cq[4];
                #pragma unroll
                for (int q = 0; q < 4; ++q) {
                    sq[q] = __shfl(colv[q], ei);
                    cq[q] = __shfl(civ[q], ei);
                }
                #pragma unroll
                for (int q = 0; q < 4; ++q) {
                    if (lane_ok && ei < jnq[q]) {
                        float4 f = feat4[(size_t)sq[q] * 12 + d4];
                        acc[q].x = fmaf(f.x, cq[q], acc[q].x);
                        acc[q].y = fmaf(f.y, cq[q], acc[q].y);
                        acc[q].z = fmaf(f.z, cq[q], acc[q].z);
                        acc[q].w = fmaf(f.w, cq[q], acc[q].w);
                    }
                }
            }
        }
        #pragma unroll
        for (int q = 0; q < 4; ++q) {
            // reduce 5 edge slots onto lanes 0..11 (temps BEFORE update: no aliasing)
            float4 a = acc[q];
            float x1 = __shfl(a.x, lane + 12), x2 = __shfl(a.x, lane + 24);
            float x3 = __shfl(a.x, lane + 36), x4 = __shfl(a.x, lane + 48);
            float y1 = __shfl(a.y, lane + 12), y2 = __shfl(a.y, lane + 24);
            float y3 = __shfl(a.y, lane + 36), y4 = __shfl(a.y, lane + 48);
            float z1 = __shfl(a.z, lane + 12), z2 = __shfl(a.z, lane + 24);
            float z3 = __shfl(a.z, lane + 36), z4 = __shfl(a.z, lane + 48);
            float w1 = __shfl(a.w, lane + 12), w2 = __shfl(a.w, lane + 24);
            float w3 = __shfl(a.w, lane + 36), w4 = __shfl(a.w, lane + 48);
            a.x += (x1 + x2) + (x3 + x4);
            a.y += (y1 + y2) + (y3 + y4);
            a.z += (z1 + z2) + (z3 + z4);
            a.w += (w1 + w2) + (w3 + w4);
            int nl = nl0 + q;
            int n = bin * NPB_D + nl;
            if (lane < 12 && n < N_NODES) {
                float4 res;
                int deg = degq[q];
                if (deg > 0) {
                    float cj = rsqrtf((float)deg);
                    res = make_float4(a.x * cj, a.y * cj, a.z * cj, a.w * cj);
                } else {
                    res = feat4[(size_t)n * 12 + d4];
                }
                *(float4*)(U.p3.hl + nl * HS + d4 * 4) = res;
            }
        }
        __syncthreads();

        // ---- Phase C: out = relu(h @ W^T + b), b128 LDS reads ----
        {
            int nl = tid >> 4;
            int c = tid & 15;
            int n = bin * NPB_D + nl;
            if (n < N_NODES) {
                float a0 = U.p3.bl[c], a1 = U.p3.bl[c + 16], a2 = U.p3.bl[c + 32];
                #pragma unroll
                for (int k4 = 0; k4 < 12; ++k4) {
                    float4 hv = *(const float4*)(U.p3.hl + nl * HS + k4 * 4);
                    float4 w0 = *(const float4*)(U.p3.Wl + c * HS + k4 * 4);
                    float4 w1 = *(const float4*)(U.p3.Wl + (c + 16) * HS + k4 * 4);
                    float4 w2 = *(const float4*)(U.p3.Wl + (c + 32) * HS + k4 * 4);
                    a0 = fmaf(hv.x, w0.x, a0); a0 = fmaf(hv.y, w0.y, a0);
                    a0 = fmaf(hv.z, w0.z, a0); a0 = fmaf(hv.w, w0.w, a0);
                    a1 = fmaf(hv.x, w1.x, a1); a1 = fmaf(hv.y, w1.y, a1);
                    a1 = fmaf(hv.z, w1.z, a1); a1 = fmaf(hv.w, w1.w, a1);
                    a2 = fmaf(hv.x, w2.x, a2); a2 = fmaf(hv.y, w2.y, a2);
                    a2 = fmaf(hv.z, w2.z, a2); a2 = fmaf(hv.w, w2.w, a2);
                }
                float* op = out + (size_t)n * D;
                op[c]      = fmaxf(a0, 0.0f);
                op[c + 16] = fmaxf(a1, 0.0f);
                op[c + 32] = fmaxf(a2, 0.0f);
            }
        }
    }
}

extern "C" void kernel_launch(void* const* d_in, const int* in_sizes, int n_in,
                              void* d_out, int out_size, void* d_ws, size_t ws_size,
                              hipStream_t stream) {
    const float* feat = (const float*)d_in[0];
    const int*   src  = (const int*)d_in[1];
    const int*   dst  = (const int*)d_in[2];
    const float* W    = (const float*)d_in[3];
    const float* b    = (const float*)d_in[4];
    float* out = (float*)d_out;

    char* ws = (char*)d_ws;
    unsigned int*   rec   = (unsigned int*)(ws + RECD_OFF);
    unsigned char*  srcb  = (unsigned char*)(ws + SRCB_OFF);
    float*          ci    = (float*)(ws + CI_OFF);
    unsigned short* offld = (unsigned short*)(ws + OFFLD_OFF);
    unsigned short* offls = (unsigned short*)(ws + OFFLS_OFF);
    int*            bar   = (int*)(ws + BAR_OFF);

    hipMemsetAsync(bar, 0, 8, stream);
    k_fused<<<NB, TPB, 0, stream>>>(src, dst, feat, W, b, out,
                                    rec, srcb, ci, offld, offls, bar);
}

// Round 14
// 167.260 us; speedup vs baseline: 1.4170x; 1.4170x over previous
//
#include <hip/hip_runtime.h>

#define N_NODES 50000
#define N_EDGES 1600000
#define D 48

#define EPB 8192            // edges per prep block
#define PB  196             // ceil(N_EDGES/EPB)
#define NPB_D 64
#define NBIN_D 782          // ceil(50000/64)
#define NPB_S 256
#define NBIN_S 196          // ceil(50000/256)

#define EMAX 3072           // per-dst-bin edge cap (mean 2048, sigma ~45)
#define HS 52               // h/W LDS stride (16B-aligned, bank-spread; proven R10)

// ---------- workspace layout (bytes), total ~8.61 MB ----------
#define RECD_OFF  0          // u32[PB*EPB] block-major: (src<<6)|dlocal
#define SRCB_OFF  6422528    // u8 [PB*EPB] block-major: src&255
#define CI_OFF    8028160    // f32[50000]
#define OFFLD_OFF 8228160    // u16[PB][NBIN_D+1]
#define OFFLS_OFF 8535096    // u16[PB][NBIN_S+1]

// One kernel = count + scan + scatter, all block-local. Coalesced output only.
__global__ __launch_bounds__(1024) void k_prep(const int* __restrict__ src,
                                               const int* __restrict__ dst,
                                               unsigned int* __restrict__ rec,
                                               unsigned char* __restrict__ srcb,
                                               unsigned short* __restrict__ offld,
                                               unsigned short* __restrict__ offls) {
    __shared__ int cd[NBIN_D];                  // histogram, then cursor
    __shared__ int cs[NBIN_S];
    __shared__ int scan[1024];
    __shared__ alignas(16) unsigned int  bufd[EPB];
    __shared__ alignas(16) unsigned char bufs[EPB];
    int tid = threadIdx.x, p = blockIdx.x;
    int base = p * EPB;

    int sv[8], dv[8];
    bool ok[8];
    #pragma unroll
    for (int k = 0; k < 8; ++k) {
        int e = base + tid + k * 1024;
        ok[k] = (e < N_EDGES);
        sv[k] = ok[k] ? src[e] : 0;
        dv[k] = ok[k] ? dst[e] : 0;
    }

    for (int i = tid; i < NBIN_D; i += 1024) cd[i] = 0;
    for (int i = tid; i < NBIN_S; i += 1024) cs[i] = 0;
    __syncthreads();
    #pragma unroll
    for (int k = 0; k < 8; ++k) {
        if (ok[k]) {
            atomicAdd(&cd[dv[k] >> 6], 1);
            atomicAdd(&cs[sv[k] >> 8], 1);
        }
    }
    __syncthreads();

    // one fused Hillis-Steele scan over [cd | cs] (782 + 196 = 978 <= 1024)
    int own = 0;
    if (tid < NBIN_D) own = cd[tid];
    else if (tid < NBIN_D + NBIN_S) own = cs[tid - NBIN_D];
    scan[tid] = own;
    __syncthreads();
    for (int o = 1; o < 1024; o <<= 1) {
        int x = (tid >= o) ? scan[tid - o] : 0;
        __syncthreads();
        scan[tid] += x;
        __syncthreads();
    }
    int incl = scan[tid];
    int cdt = scan[NBIN_D - 1];                 // total dst-side count
    __syncthreads();

    if (tid < NBIN_D) {
        int ex = incl - own;
        offld[p * (NBIN_D + 1) + tid] = (unsigned short)ex;
        cd[tid] = ex;                           // cursor
        if (tid == NBIN_D - 1) offld[p * (NBIN_D + 1) + NBIN_D] = (unsigned short)incl;
    } else if (tid < NBIN_D + NBIN_S) {
        int t = tid - NBIN_D;
        int ex = (incl - cdt) - own;
        offls[p * (NBIN_S + 1) + t] = (unsigned short)ex;
        cs[t] = ex;                             // cursor
        if (t == NBIN_S - 1) offls[p * (NBIN_S + 1) + NBIN_S] = (unsigned short)(incl - cdt);
    }
    __syncthreads();

    #pragma unroll
    for (int k = 0; k < 8; ++k) {
        if (ok[k]) {
            int s = sv[k], d = dv[k];
            int pd = atomicAdd(&cd[d >> 6], 1);
            bufd[pd] = ((unsigned int)s << 6) | (unsigned int)(d & 63);
            int ps = atomicAdd(&cs[s >> 8], 1);
            bufs[ps] = (unsigned char)s;
        }
    }
    __syncthreads();

    // coalesced full-line streams out
    int4* ro = (int4*)(rec + base);
    const int4* bi = (const int4*)bufd;
    for (int i = tid; i < EPB / 4; i += 1024) ro[i] = bi[i];
    unsigned int* so = (unsigned int*)(srcb + base);
    const unsigned int* bs = (const unsigned int*)bufs;
    for (int i = tid; i < EPB / 4; i += 1024) so[i] = bs[i];
}

// one block per src-bin: gather its PB runs, LDS histogram -> ci
__global__ __launch_bounds__(512) void k_ci(const unsigned char* __restrict__ srcb,
                                            const unsigned short* __restrict__ offls,
                                            float* __restrict__ ci) {
    __shared__ int cnt[NPB_S];
    int tid = threadIdx.x, sb = blockIdx.x;
    for (int i = tid; i < NPB_S; i += 512) cnt[i] = 0;
    __syncthreads();
    int wave = tid >> 6, lane = tid & 63;
    for (int p = wave; p < PB; p += 8) {
        int beg = offls[p * (NBIN_S + 1) + sb];
        int end = offls[p * (NBIN_S + 1) + sb + 1];
        for (int j = beg + lane; j < end; j += 64)
            atomicAdd(&cnt[srcb[p * EPB + j]], 1);
    }
    __syncthreads();
    int n = sb * NPB_S + tid;
    if (tid < NPB_S && n < N_NODES)
        ci[n] = rsqrtf(fmaxf((float)cnt[tid], 1.0f));
}

// Fused CSR-build + gather + GEMM: one block (16 waves) per 64-node dst-bin.
__global__ __launch_bounds__(1024, 8) void k_gcn(
    const unsigned int* __restrict__ rec, const unsigned short* __restrict__ offld,
    const float* __restrict__ ci, const float* __restrict__ feat,
    const float* __restrict__ W, const float* __restrict__ b,
    float* __restrict__ out) {
    __shared__ int   craw[EMAX];        // raw records (arbitrary order)
    __shared__ int   colb[EMAX];        // reordered local col (src ids)
    __shared__ float hl[NPB_D * HS];
    __shared__ float Wl[D * HS];
    __shared__ float bl[D];
    __shared__ int   ideg[NPB_D];
    __shared__ int   off[NPB_D];
    __shared__ int   cur[NPB_D];
    __shared__ int   runoff[PB + 1];    // exclusive scan of run lengths
    __shared__ int   runpos[PB];        // absolute start index in rec
    __shared__ int   rs[256];
    int tid = threadIdx.x, bin = blockIdx.x;

    for (int i = tid; i < D * D; i += 1024) Wl[(i / D) * HS + (i % D)] = W[i];
    if (tid < D) bl[tid] = b[tid];
    if (tid < NPB_D) { ideg[tid] = 0; cur[tid] = 0; }

    // ---- run table + scan of run lengths ----
    int rlen = 0;
    if (tid < PB) {
        int o0 = offld[tid * (NBIN_D + 1) + bin];
        int o1 = offld[tid * (NBIN_D + 1) + bin + 1];
        rlen = o1 - o0;
        runpos[tid] = tid * EPB + o0;
    }
    if (tid < 256) rs[tid] = (tid < PB) ? rlen : 0;
    __syncthreads();
    for (int o = 1; o < 256; o <<= 1) {
        int x = 0;
        if (tid < 256 && tid >= o) x = rs[tid - o];
        __syncthreads();
        if (tid < 256) rs[tid] += x;
        __syncthreads();
    }
    if (tid < PB) runoff[tid] = rs[tid] - rlen;
    if (tid == 0) runoff[PB] = rs[PB - 1];
    __syncthreads();
    int cnt = runoff[PB];
    if (cnt > EMAX) cnt = EMAX;         // unreachable; guards LDS OOB

    // ---- Phase A: gather runs (binary search), histogram, scan, reorder ----
    for (int j = tid; j < cnt; j += 1024) {
        int lo = 0, hi = PB - 1;
        while (lo < hi) {
            int mid = (lo + hi + 1) >> 1;
            if (runoff[mid] <= j) lo = mid; else hi = mid - 1;
        }
        unsigned int r = rec[runpos[lo] + (j - runoff[lo])];
        craw[j] = (int)r;
        atomicAdd(&ideg[r & 63], 1);
    }
    __syncthreads();
    if (tid < NPB_D) {
        int v = ideg[tid];
        int incl = v;
        for (int o = 1; o < 64; o <<= 1) {
            int u = __shfl_up(incl, o);
            if (tid >= o) incl += u;
        }
        off[tid] = incl - v;
    }
    __syncthreads();
    for (int j = tid; j < cnt; j += 1024) {
        int r = craw[j];
        int dl = r & 63;
        int p = atomicAdd(&cur[dl], 1);
        colb[off[dl] + p] = r >> 6;
    }
    __syncthreads();

    // ---- Phase B: ILP-4 float4-lane gather (4 nodes per wave, interleaved) ----
    int wave = tid >> 6;
    int lane = tid & 63;
    int eslot = lane / 12;              // 0..5 (slot 5 inactive)
    int d4 = lane - eslot * 12;         // 0..11
    bool lane_ok = (lane < 60);
    const float4* feat4 = (const float4*)feat;

    int nl0 = wave * 4;
    int degq[4], cbq[4];
    float4 acc[4];
    #pragma unroll
    for (int q = 0; q < 4; ++q) {
        degq[q] = ideg[nl0 + q];
        cbq[q] = off[nl0 + q];
        acc[q] = make_float4(0.0f, 0.0f, 0.0f, 0.0f);
    }
    int maxdeg = max(max(degq[0], degq[1]), max(degq[2], degq[3]));
    for (int c0 = 0; c0 < maxdeg; c0 += 60) {
        int colv[4]; float civ[4]; int jnq[4];
        #pragma unroll
        for (int q = 0; q < 4; ++q) {
            int jn = degq[q] - c0;
            jnq[q] = jn < 60 ? jn : 60;
            colv[q] = (lane < jnq[q]) ? colb[cbq[q] + c0 + lane] : 0;
            civ[q]  = (lane < jnq[q]) ? ci[colv[q]] : 0.0f;
        }
        int rem = maxdeg - c0;
        int maxjn = rem < 60 ? rem : 60;
        for (int i = 0; i < maxjn; i += 5) {
            int ei = i + eslot;
            // shfls UNCONDITIONAL (full exec): ds_bpermute from an
            // exec-masked-off source lane is undefined — R12's bug.
            int sq[4]; float cq[4];
            #pragma unroll
            for (int q = 0; q < 4; ++q) {
                sq[q] = __shfl(colv[q], ei);
                cq[q] = __shfl(civ[q], ei);
            }
            #pragma unroll
            for (int q = 0; q < 4; ++q) {
                if (lane_ok && ei < jnq[q]) {
                    float4 f = feat4[(size_t)sq[q] * 12 + d4];
                    acc[q].x = fmaf(f.x, cq[q], acc[q].x);
                    acc[q].y = fmaf(f.y, cq[q], acc[q].y);
                    acc[q].z = fmaf(f.z, cq[q], acc[q].z);
                    acc[q].w = fmaf(f.w, cq[q], acc[q].w);
                }
            }
        }
    }
    #pragma unroll
    for (int q = 0; q < 4; ++q) {
        // reduce 5 edge slots onto lanes 0..11 (temps BEFORE update: no aliasing)
        float4 a = acc[q];
        float x1 = __shfl(a.x, lane + 12), x2 = __shfl(a.x, lane + 24);
        float x3 = __shfl(a.x, lane + 36), x4 = __shfl(a.x, lane + 48);
        float y1 = __shfl(a.y, lane + 12), y2 = __shfl(a.y, lane + 24);
        float y3 = __shfl(a.y, lane + 36), y4 = __shfl(a.y, lane + 48);
        float z1 = __shfl(a.z, lane + 12), z2 = __shfl(a.z, lane + 24);
        float z3 = __shfl(a.z, lane + 36), z4 = __shfl(a.z, lane + 48);
        float w1 = __shfl(a.w, lane + 12), w2 = __shfl(a.w, lane + 24);
        float w3 = __shfl(a.w, lane + 36), w4 = __shfl(a.w, lane + 48);
        a.x += (x1 + x2) + (x3 + x4);
        a.y += (y1 + y2) + (y3 + y4);
        a.z += (z1 + z2) + (z3 + z4);
        a.w += (w1 + w2) + (w3 + w4);
        int nl = nl0 + q;
        int n = bin * NPB_D + nl;
        if (lane < 12 && n < N_NODES) {
            float4 res;
            int deg = degq[q];
            if (deg > 0) {
                float cj = rsqrtf((float)deg);
                res = make_float4(a.x * cj, a.y * cj, a.z * cj, a.w * cj);
            } else {
                res = feat4[(size_t)n * 12 + d4];
            }
            *(float4*)(hl + nl * HS + d4 * 4) = res;
        }
    }
    __syncthreads();

    // ---- Phase C: out = relu(h @ W^T + b), b128 LDS reads ----
    {
        int nl = tid >> 4;              // 0..63
        int c = tid & 15;               // od = c, c+16, c+32
        int n = bin * NPB_D + nl;
        if (n < N_NODES) {
            float a0 = bl[c], a1 = bl[c + 16], a2 = bl[c + 32];
            #pragma unroll
            for (int k4 = 0; k4 < 12; ++k4) {
                float4 hv = *(const float4*)(hl + nl * HS + k4 * 4);
                float4 w0 = *(const float4*)(Wl + c * HS + k4 * 4);
                float4 w1 = *(const float4*)(Wl + (c + 16) * HS + k4 * 4);
                float4 w2 = *(const float4*)(Wl + (c + 32) * HS + k4 * 4);
                a0 = fmaf(hv.x, w0.x, a0); a0 = fmaf(hv.y, w0.y, a0);
                a0 = fmaf(hv.z, w0.z, a0); a0 = fmaf(hv.w, w0.w, a0);
                a1 = fmaf(hv.x, w1.x, a1); a1 = fmaf(hv.y, w1.y, a1);
                a1 = fmaf(hv.z, w1.z, a1); a1 = fmaf(hv.w, w1.w, a1);
                a2 = fmaf(hv.x, w2.x, a2); a2 = fmaf(hv.y, w2.y, a2);
                a2 = fmaf(hv.z, w2.z, a2); a2 = fmaf(hv.w, w2.w, a2);
            }
            float* op = out + (size_t)n * D;
            op[c]      = fmaxf(a0, 0.0f);
            op[c + 16] = fmaxf(a1, 0.0f);
            op[c + 32] = fmaxf(a2, 0.0f);
        }
    }
}

extern "C" void kernel_launch(void* const* d_in, const int* in_sizes, int n_in,
                              void* d_out, int out_size, void* d_ws, size_t ws_size,
                              hipStream_t stream) {
    const float* feat = (const float*)d_in[0];
    const int*   src  = (const int*)d_in[1];
    const int*   dst  = (const int*)d_in[2];
    const float* W    = (const float*)d_in[3];
    const float* b    = (const float*)d_in[4];
    float* out = (float*)d_out;

    char* ws = (char*)d_ws;
    unsigned int*   rec   = (unsigned int*)(ws + RECD_OFF);
    unsigned char*  srcb  = (unsigned char*)(ws + SRCB_OFF);
    float*          ci    = (float*)(ws + CI_OFF);
    unsigned short* offld = (unsigned short*)(ws + OFFLD_OFF);
    unsigned short* offls = (unsigned short*)(ws + OFFLS_OFF);

    k_prep<<<PB, 1024, 0, stream>>>(src, dst, rec, srcb, offld, offls);
    k_ci<<<NBIN_S, 512, 0, stream>>>(srcb, offls, ci);
    k_gcn<<<NBIN_D, 1024, 0, stream>>>(rec, offld, ci, feat, W, b, out);
}

// Round 15
// 147.569 us; speedup vs baseline: 1.6061x; 1.1334x over previous
//
#include <hip/hip_runtime.h>

#define N_NODES 50000
#define N_EDGES 1600000
#define D 48

#define EPB 8192            // edges per prep block
#define PB  196             // ceil(N_EDGES/EPB)
#define NPB_D 64
#define NBIN_D 782          // ceil(50000/64)
#define NPB_S 256
#define NBIN_S 196          // ceil(50000/256)

#define EMAX 3072           // per-dst-bin edge cap (mean 2048, sigma ~45)
#define HS 52               // h/W LDS stride (16B-aligned, bank-spread; proven R10)

// ---------- workspace layout (bytes) ----------
#define RECD_OFF  0          // u32[PB*EPB] block-major: (src<<6)|dlocal
#define SRCB_OFF  6422528    // u8 [PB*EPB] block-major: src&255
#define OFFLD_OFF 8028160    // u16[PB][NBIN_D+1]
#define OFFLS_OFF 8335104    // u16[PB][NBIN_S+1]
#define CI_OFF    8412416    // f32[50000]
#define SFEAT_OFF 8612416    // f32[50000*48] prescaled (optional)
#define SFEAT_END 18212416

// One kernel = count + scan + scatter, all block-local. Coalesced output only.
__global__ __launch_bounds__(1024) void k_prep(const int* __restrict__ src,
                                               const int* __restrict__ dst,
                                               unsigned int* __restrict__ rec,
                                               unsigned char* __restrict__ srcb,
                                               unsigned short* __restrict__ offld,
                                               unsigned short* __restrict__ offls) {
    __shared__ int cd[NBIN_D];                  // histogram, then cursor
    __shared__ int cs[NBIN_S];
    __shared__ int wsum[16], wexcl[16];
    __shared__ int cdt_s;
    __shared__ alignas(16) unsigned int  bufd[EPB];
    __shared__ alignas(16) unsigned char bufs[EPB];
    int tid = threadIdx.x, p = blockIdx.x;
    int wave = tid >> 6, lane = tid & 63;
    int base = p * EPB;

    int sv[8], dv[8];
    bool ok[8];
    #pragma unroll
    for (int k = 0; k < 8; ++k) {
        int e = base + tid + k * 1024;
        ok[k] = (e < N_EDGES);
        sv[k] = ok[k] ? src[e] : 0;
        dv[k] = ok[k] ? dst[e] : 0;
    }

    for (int i = tid; i < NBIN_D; i += 1024) cd[i] = 0;
    for (int i = tid; i < NBIN_S; i += 1024) cs[i] = 0;
    __syncthreads();
    #pragma unroll
    for (int k = 0; k < 8; ++k) {
        if (ok[k]) {
            atomicAdd(&cd[dv[k] >> 6], 1);
            atomicAdd(&cs[sv[k] >> 8], 1);
        }
    }
    __syncthreads();

    // wave-shuffle scan over [cd | cs] (978 elements in threads 0..977)
    int own = 0;
    if (tid < NBIN_D) own = cd[tid];
    else if (tid < NBIN_D + NBIN_S) own = cs[tid - NBIN_D];
    int incl = own;
    #pragma unroll
    for (int o = 1; o < 64; o <<= 1) {
        int u = __shfl_up(incl, o);
        if (lane >= o) incl += u;
    }
    if (lane == 63) wsum[wave] = incl;
    __syncthreads();
    if (tid < 16) {
        int v = wsum[tid];
        int ic = v;
        #pragma unroll
        for (int o = 1; o < 16; o <<= 1) {
            int u = __shfl_up(ic, o);
            if (lane >= o) ic += u;
        }
        wexcl[tid] = ic - v;
    }
    __syncthreads();
    int gincl = wexcl[wave] + incl;             // global inclusive prefix
    if (tid == NBIN_D - 1) cdt_s = gincl;       // total dst-side count
    __syncthreads();
    int cdt = cdt_s;

    if (tid < NBIN_D) {
        int ex = gincl - own;
        offld[p * (NBIN_D + 1) + tid] = (unsigned short)ex;
        cd[tid] = ex;                           // cursor
        if (tid == NBIN_D - 1) offld[p * (NBIN_D + 1) + NBIN_D] = (unsigned short)gincl;
    } else if (tid < NBIN_D + NBIN_S) {
        int t = tid - NBIN_D;
        int ex = (gincl - cdt) - own;
        offls[p * (NBIN_S + 1) + t] = (unsigned short)ex;
        cs[t] = ex;                             // cursor
        if (t == NBIN_S - 1) offls[p * (NBIN_S + 1) + NBIN_S] = (unsigned short)(gincl - cdt);
    }
    __syncthreads();

    #pragma unroll
    for (int k = 0; k < 8; ++k) {
        if (ok[k]) {
            int s = sv[k], d = dv[k];
            int pd = atomicAdd(&cd[d >> 6], 1);
            bufd[pd] = ((unsigned int)s << 6) | (unsigned int)(d & 63);
            int ps = atomicAdd(&cs[s >> 8], 1);
            bufs[ps] = (unsigned char)s;
        }
    }
    __syncthreads();

    // coalesced full-line streams out
    int4* ro = (int4*)(rec + base);
    const int4* bi = (const int4*)bufd;
    for (int i = tid; i < EPB / 4; i += 1024) ro[i] = bi[i];
    unsigned int* so = (unsigned int*)(srcb + base);
    const unsigned int* bs = (const unsigned int*)bufs;
    for (int i = tid; i < EPB / 4; i += 1024) so[i] = bs[i];
}

// one block per src-bin: gather its PB runs, LDS histogram -> ci (+ sfeat)
__global__ __launch_bounds__(512) void k_ci(const unsigned char* __restrict__ srcb,
                                            const unsigned short* __restrict__ offls,
                                            const float* __restrict__ feat,
                                            float* __restrict__ ci,
                                            float* __restrict__ sfeat,
                                            int do_scale) {
    __shared__ int cnt[NPB_S];
    __shared__ float cl[NPB_S];
    int tid = threadIdx.x, sb = blockIdx.x;
    for (int i = tid; i < NPB_S; i += 512) cnt[i] = 0;
    __syncthreads();
    int wave = tid >> 6, lane = tid & 63;
    for (int p = wave; p < PB; p += 8) {
        int beg = offls[p * (NBIN_S + 1) + sb];
        int end = offls[p * (NBIN_S + 1) + sb + 1];
        for (int j = beg + lane; j < end; j += 64)
            atomicAdd(&cnt[srcb[p * EPB + j]], 1);
    }
    __syncthreads();
    if (tid < NPB_S) {
        float c = rsqrtf(fmaxf((float)cnt[tid], 1.0f));
        cl[tid] = c;
        int n = sb * NPB_S + tid;
        if (n < N_NODES) ci[n] = c;
    }
    __syncthreads();
    if (do_scale) {
        int nb = sb * NPB_S;
        int lim4 = (min(NPB_S, N_NODES - nb)) * 12;   // float4s in this bin
        const float4* f4 = (const float4*)feat + (size_t)nb * 12;
        float4* s4 = (float4*)sfeat + (size_t)nb * 12;
        for (int i = tid; i < lim4; i += 512) {
            float sc = cl[i / 12];
            float4 f = f4[i];
            s4[i] = make_float4(f.x * sc, f.y * sc, f.z * sc, f.w * sc);
        }
    }
}

// Fused CSR-build + gather + GEMM: one block (8 waves, 512 thr) per 64-node bin.
// 4 blocks/CU (wave cap) -> all 782 blocks co-resident, no tail rounds.
template <bool PRESCALED>
__global__ __launch_bounds__(512, 8) void k_gcn(
    const unsigned int* __restrict__ rec, const unsigned short* __restrict__ offld,
    const float* __restrict__ ci, const float* __restrict__ sfeat,
    const float* __restrict__ feat,
    const float* __restrict__ W, const float* __restrict__ b,
    float* __restrict__ out) {
    __shared__ int   colb[EMAX];        // 12.3 KB reordered local col (src ids)
    __shared__ float hl[NPB_D * HS];    // 13.3 KB
    __shared__ float Wl[D * HS];        // 10.0 KB
    __shared__ float bl[D];
    __shared__ int   ideg[NPB_D];
    __shared__ int   off[NPB_D];
    __shared__ int   cur[NPB_D];
    __shared__ int   runoff[PB + 1];
    __shared__ int   runpos[PB];
    __shared__ int   wsum[8], wexcl[8];
    int tid = threadIdx.x, bin = blockIdx.x;
    int wave = tid >> 6, lane = tid & 63;

    for (int i = tid; i < D * D; i += 512) Wl[(i / D) * HS + (i % D)] = W[i];
    if (tid < D) bl[tid] = b[tid];
    if (tid < NPB_D) { ideg[tid] = 0; cur[tid] = 0; }

    // ---- run table + wave-shuffle scan of run lengths ----
    int rlen = 0;
    if (tid < PB) {
        int o0 = offld[tid * (NBIN_D + 1) + bin];
        int o1 = offld[tid * (NBIN_D + 1) + bin + 1];
        rlen = o1 - o0;
        runpos[tid] = tid * EPB + o0;
    }
    int incl = rlen;
    #pragma unroll
    for (int o = 1; o < 64; o <<= 1) {
        int u = __shfl_up(incl, o);
        if (lane >= o) incl += u;
    }
    if (lane == 63) wsum[wave] = incl;
    __syncthreads();
    if (tid < 8) {
        int v = wsum[tid];
        int ic = v;
        #pragma unroll
        for (int o = 1; o < 8; o <<= 1) {
            int u = __shfl_up(ic, o);
            if (lane >= o) ic += u;
        }
        wexcl[tid] = ic - v;
        if (tid == 7) runoff[PB] = ic;
    }
    __syncthreads();
    if (tid < PB) runoff[tid] = wexcl[wave] + incl - rlen;
    __syncthreads();
    int cnt = runoff[PB];
    if (cnt > EMAX) cnt = EMAX;         // unreachable; guards LDS OOB

    // ---- Phase A: gather runs into regs (binary search), histogram, scan, reorder ----
    unsigned int rr[6];
    #pragma unroll
    for (int k = 0; k < 6; ++k) {
        int j = tid + k * 512;
        rr[k] = 0xFFFFFFFFu;
        if (j < cnt) {
            int lo = 0, hi = PB - 1;
            while (lo < hi) {
                int mid = (lo + hi + 1) >> 1;
                if (runoff[mid] <= j) lo = mid; else hi = mid - 1;
            }
            unsigned int r = rec[runpos[lo] + (j - runoff[lo])];
            rr[k] = r;
            atomicAdd(&ideg[r & 63], 1);
        }
    }
    __syncthreads();
    if (tid < NPB_D) {
        int v = ideg[tid];
        int ic = v;
        #pragma unroll
        for (int o = 1; o < 64; o <<= 1) {
            int u = __shfl_up(ic, o);
            if (tid >= o) ic += u;
        }
        off[tid] = ic - v;
    }
    __syncthreads();
    #pragma unroll
    for (int k = 0; k < 6; ++k) {
        if (rr[k] != 0xFFFFFFFFu) {
            int dl = rr[k] & 63;
            int p = atomicAdd(&cur[dl], 1);
            colb[off[dl] + p] = (int)(rr[k] >> 6);
        }
    }
    __syncthreads();

    // ---- Phase B: float4-lane gather, 8 nodes per wave (serial q; compiler pipelines) ----
    int eslot = lane / 12;              // 0..5 (slot 5 inactive)
    int d4 = lane - eslot * 12;         // 0..11
    bool lane_ok = (lane < 60);
    const float4* feat4 = (const float4*)feat;
    const float4* sf4 = (const float4*)sfeat;

    for (int q = 0; q < 8; ++q) {
        int nl = wave * 8 + q;
        int n = bin * NPB_D + nl;
        int cb = off[nl];
        int deg = ideg[nl];

        float4 acc = make_float4(0.0f, 0.0f, 0.0f, 0.0f);
        for (int c0 = 0; c0 < deg; c0 += 60) {
            int jn = min(60, deg - c0);
            int colv = (lane < jn) ? colb[cb + c0 + lane] : 0;
            float civ = 0.0f;
            if (!PRESCALED) civ = (lane < jn) ? ci[colv] : 0.0f;
            for (int i = 0; i < jn; i += 5) {
                int ei = i + eslot;
                // shfls unconditional (full exec) — masked-source bpermute is undefined (R12 bug)
                int s = __shfl(colv, ei);
                float c = PRESCALED ? 0.0f : __shfl(civ, ei);
                if (lane_ok && ei < jn) {
                    if (PRESCALED) {
                        float4 f = sf4[(size_t)s * 12 + d4];
                        acc.x += f.x; acc.y += f.y; acc.z += f.z; acc.w += f.w;
                    } else {
                        float4 f = feat4[(size_t)s * 12 + d4];
                        acc.x = fmaf(f.x, c, acc.x);
                        acc.y = fmaf(f.y, c, acc.y);
                        acc.z = fmaf(f.z, c, acc.z);
                        acc.w = fmaf(f.w, c, acc.w);
                    }
                }
            }
        }
        // reduce 5 edge slots onto lanes 0..11 (temps BEFORE update: no aliasing)
        {
            float x1 = __shfl(acc.x, lane + 12), x2 = __shfl(acc.x, lane + 24);
            float x3 = __shfl(acc.x, lane + 36), x4 = __shfl(acc.x, lane + 48);
            float y1 = __shfl(acc.y, lane + 12), y2 = __shfl(acc.y, lane + 24);
            float y3 = __shfl(acc.y, lane + 36), y4 = __shfl(acc.y, lane + 48);
            float z1 = __shfl(acc.z, lane + 12), z2 = __shfl(acc.z, lane + 24);
            float z3 = __shfl(acc.z, lane + 36), z4 = __shfl(acc.z, lane + 48);
            float w1 = __shfl(acc.w, lane + 12), w2 = __shfl(acc.w, lane + 24);
            float w3 = __shfl(acc.w, lane + 36), w4 = __shfl(acc.w, lane + 48);
            acc.x += (x1 + x2) + (x3 + x4);
            acc.y += (y1 + y2) + (y3 + y4);
            acc.z += (z1 + z2) + (z3 + z4);
            acc.w += (w1 + w2) + (w3 + w4);
        }
        if (lane < 12 && n < N_NODES) {
            float4 res;
            if (deg > 0) {
                float cj = rsqrtf((float)deg);
                res = make_float4(acc.x * cj, acc.y * cj, acc.z * cj, acc.w * cj);
            } else {
                res = feat4[(size_t)n * 12 + d4];
            }
            *(float4*)(hl + nl * HS + d4 * 4) = res;
        }
    }
    __syncthreads();

    // ---- Phase C: out = relu(h @ W^T + b), b128 LDS reads; 2 node-halves ----
    #pragma unroll
    for (int half = 0; half < 2; ++half) {
        int nl = (tid >> 4) + half * 32;
        int c = tid & 15;               // od = c, c+16, c+32
        int n = bin * NPB_D + nl;
        if (n < N_NODES) {
            float a0 = bl[c], a1 = bl[c + 16], a2 = bl[c + 32];
            #pragma unroll
            for (int k4 = 0; k4 < 12; ++k4) {
                float4 hv = *(const float4*)(hl + nl * HS + k4 * 4);
                float4 w0 = *(const float4*)(Wl + c * HS + k4 * 4);
                float4 w1 = *(const float4*)(Wl + (c + 16) * HS + k4 * 4);
                float4 w2 = *(const float4*)(Wl + (c + 32) * HS + k4 * 4);
                a0 = fmaf(hv.x, w0.x, a0); a0 = fmaf(hv.y, w0.y, a0);
                a0 = fmaf(hv.z, w0.z, a0); a0 = fmaf(hv.w, w0.w, a0);
                a1 = fmaf(hv.x, w1.x, a1); a1 = fmaf(hv.y, w1.y, a1);
                a1 = fmaf(hv.z, w1.z, a1); a1 = fmaf(hv.w, w1.w, a1);
                a2 = fmaf(hv.x, w2.x, a2); a2 = fmaf(hv.y, w2.y, a2);
                a2 = fmaf(hv.z, w2.z, a2); a2 = fmaf(hv.w, w2.w, a2);
            }
            float* op = out + (size_t)n * D;
            op[c]      = fmaxf(a0, 0.0f);
            op[c + 16] = fmaxf(a1, 0.0f);
            op[c + 32] = fmaxf(a2, 0.0f);
        }
    }
}

extern "C" void kernel_launch(void* const* d_in, const int* in_sizes, int n_in,
                              void* d_out, int out_size, void* d_ws, size_t ws_size,
                              hipStream_t stream) {
    const float* feat = (const float*)d_in[0];
    const int*   src  = (const int*)d_in[1];
    const int*   dst  = (const int*)d_in[2];
    const float* W    = (const float*)d_in[3];
    const float* b    = (const float*)d_in[4];
    float* out = (float*)d_out;

    char* ws = (char*)d_ws;
    unsigned int*   rec   = (unsigned int*)(ws + RECD_OFF);
    unsigned char*  srcb  = (unsigned char*)(ws + SRCB_OFF);
    unsigned short* offld = (unsigned short*)(ws + OFFLD_OFF);
    unsigned short* offls = (unsigned short*)(ws + OFFLS_OFF);
    float*          ci    = (float*)(ws + CI_OFF);
    float*          sfeat = (float*)(ws + SFEAT_OFF);

    const bool prescale = (ws_size >= (size_t)SFEAT_END);

    k_prep<<<PB, 1024, 0, stream>>>(src, dst, rec, srcb, offld, offls);
    k_ci<<<NBIN_S, 512, 0, stream>>>(srcb, offls, feat, ci, sfeat, prescale ? 1 : 0);
    if (prescale)
        k_gcn<true><<<NBIN_D, 512, 0, stream>>>(rec, offld, ci, sfeat, feat, W, b, out);
    else
        k_gcn<false><<<NBIN_D, 512, 0, stream>>>(rec, offld, ci, sfeat, feat, W, b, out);
}

// Round 16
// 141.634 us; speedup vs baseline: 1.6734x; 1.0419x over previous
//
#include <hip/hip_runtime.h>
#include <hip/hip_fp16.h>

#define N_NODES 50000
#define N_EDGES 1600000
#define D 48

#define EPB 8192            // edges per prep block
#define PB  196             // ceil(N_EDGES/EPB)
#define NPB_D 50            // dst-bin size: 1000 bins exactly, balanced 4/CU grid
#define NBIN_D 1000
#define NPB_S 256
#define NBIN_S 196          // ceil(50000/256)

#define EMAX 2400           // per-dst-bin edge cap (mean 1600, sigma ~40 -> 20 sigma)
#define HS 52               // h/W LDS stride (16B-aligned, bank-spread; proven R10)

// ---------- workspace layout (bytes) ----------
#define RECD_OFF  0          // u32[PB*EPB] block-major: (src<<6)|dlocal
#define SRCB_OFF  6422528    // u8 [PB*EPB] block-major: src&255
#define OFFLD_OFF 8028160    // u16[PB][NBIN_D+1]
#define OFFLS_OFF 8420552    // u16[PB][NBIN_S+1]
#define CI_OFF    8497776    // f32[50000]
#define SFEAT_OFF 8697776    // f16[50000*48] prescaled (optional)
#define SFEAT_END 13497776

// One kernel = count + scan + scatter, all block-local. Coalesced output only.
__global__ __launch_bounds__(1024) void k_prep(const int* __restrict__ src,
                                               const int* __restrict__ dst,
                                               unsigned int* __restrict__ rec,
                                               unsigned char* __restrict__ srcb,
                                               unsigned short* __restrict__ offld,
                                               unsigned short* __restrict__ offls) {
    __shared__ int cd[NBIN_D];                  // histogram, then cursor
    __shared__ int cs[NBIN_S];
    __shared__ int wsum[16], wexcl[16];
    __shared__ int wsum2[4], wexcl2[4];
    __shared__ alignas(16) unsigned int  bufd[EPB];
    __shared__ alignas(16) unsigned char bufs[EPB];
    int tid = threadIdx.x, p = blockIdx.x;
    int wave = tid >> 6, lane = tid & 63;
    int base = p * EPB;

    int sv[8], dv[8];
    bool ok[8];
    #pragma unroll
    for (int k = 0; k < 8; ++k) {
        int e = base + tid + k * 1024;
        ok[k] = (e < N_EDGES);
        sv[k] = ok[k] ? src[e] : 0;
        dv[k] = ok[k] ? dst[e] : 0;
    }

    for (int i = tid; i < NBIN_D; i += 1024) cd[i] = 0;
    for (int i = tid; i < NBIN_S; i += 1024) cs[i] = 0;
    __syncthreads();
    #pragma unroll
    for (int k = 0; k < 8; ++k) {
        if (ok[k]) {
            atomicAdd(&cd[dv[k] / NPB_D], 1);
            atomicAdd(&cs[sv[k] >> 8], 1);
        }
    }
    __syncthreads();

    // wave-shuffle scan over cd (1000 elements, threads 0..999)
    int own = (tid < NBIN_D) ? cd[tid] : 0;
    int incl = own;
    #pragma unroll
    for (int o = 1; o < 64; o <<= 1) {
        int u = __shfl_up(incl, o);
        if (lane >= o) incl += u;
    }
    if (lane == 63) wsum[wave] = incl;
    __syncthreads();
    if (tid < 16) {
        int v = wsum[tid];
        int ic = v;
        #pragma unroll
        for (int o = 1; o < 16; o <<= 1) {
            int u = __shfl_up(ic, o);
            if (lane >= o) ic += u;
        }
        wexcl[tid] = ic - v;
    }
    __syncthreads();
    if (tid < NBIN_D) {
        int gincl = wexcl[wave] + incl;
        int ex = gincl - own;
        offld[p * (NBIN_D + 1) + tid] = (unsigned short)ex;
        cd[tid] = ex;                           // cursor
        if (tid == NBIN_D - 1) offld[p * (NBIN_D + 1) + NBIN_D] = (unsigned short)gincl;
    }

    // wave-shuffle scan over cs (196 elements, threads 0..195)
    int own2 = (tid < NBIN_S) ? cs[tid] : 0;
    int incl2 = own2;
    #pragma unroll
    for (int o = 1; o < 64; o <<= 1) {
        int u = __shfl_up(incl2, o);
        if (lane >= o) incl2 += u;
    }
    if (lane == 63 && wave < 4) wsum2[wave] = incl2;
    __syncthreads();
    if (tid < 4) {
        int v = wsum2[tid];
        int ic = v;
        #pragma unroll
        for (int o = 1; o < 4; o <<= 1) {
            int u = __shfl_up(ic, o);
            if (lane >= o) ic += u;
        }
        wexcl2[tid] = ic - v;
    }
    __syncthreads();
    if (tid < NBIN_S) {
        int gincl2 = wexcl2[wave] + incl2;
        int ex = gincl2 - own2;
        offls[p * (NBIN_S + 1) + tid] = (unsigned short)ex;
        cs[tid] = ex;                           // cursor
        if (tid == NBIN_S - 1) offls[p * (NBIN_S + 1) + NBIN_S] = (unsigned short)gincl2;
    }
    __syncthreads();

    #pragma unroll
    for (int k = 0; k < 8; ++k) {
        if (ok[k]) {
            int s = sv[k], d = dv[k];
            int bin = d / NPB_D;
            int pd = atomicAdd(&cd[bin], 1);
            bufd[pd] = ((unsigned int)s << 6) | (unsigned int)(d - bin * NPB_D);
            int ps = atomicAdd(&cs[s >> 8], 1);
            bufs[ps] = (unsigned char)s;
        }
    }
    __syncthreads();

    // coalesced full-line streams out
    int4* ro = (int4*)(rec + base);
    const int4* bi = (const int4*)bufd;
    for (int i = tid; i < EPB / 4; i += 1024) ro[i] = bi[i];
    unsigned int* so = (unsigned int*)(srcb + base);
    const unsigned int* bs = (const unsigned int*)bufs;
    for (int i = tid; i < EPB / 4; i += 1024) so[i] = bs[i];
}

// one block per src-bin: gather its PB runs, LDS histogram -> ci (+ fp16 sfeat)
__global__ __launch_bounds__(512) void k_ci(const unsigned char* __restrict__ srcb,
                                            const unsigned short* __restrict__ offls,
                                            const float* __restrict__ feat,
                                            float* __restrict__ ci,
                                            __half* __restrict__ sfeat,
                                            int do_scale) {
    __shared__ int cnt[NPB_S];
    __shared__ float cl[NPB_S];
    int tid = threadIdx.x, sb = blockIdx.x;
    for (int i = tid; i < NPB_S; i += 512) cnt[i] = 0;
    __syncthreads();
    int wave = tid >> 6, lane = tid & 63;
    for (int p = wave; p < PB; p += 8) {
        int beg = offls[p * (NBIN_S + 1) + sb];
        int end = offls[p * (NBIN_S + 1) + sb + 1];
        for (int j = beg + lane; j < end; j += 64)
            atomicAdd(&cnt[srcb[p * EPB + j]], 1);
    }
    __syncthreads();
    if (tid < NPB_S) {
        float c = rsqrtf(fmaxf((float)cnt[tid], 1.0f));
        cl[tid] = c;
        int n = sb * NPB_S + tid;
        if (n < N_NODES) ci[n] = c;
    }
    __syncthreads();
    if (do_scale) {
        int nb = sb * NPB_S;
        int lim2 = (min(NPB_S, N_NODES - nb)) * 24;   // half2 units (2 floats each)
        const float2* f2 = (const float2*)feat + (size_t)nb * 24;
        __half2* s2 = (__half2*)sfeat + (size_t)nb * 24;
        for (int i = tid; i < lim2; i += 512) {
            float sc = cl[i / 24];
            float2 f = f2[i];
            s2[i] = __float22half2_rn(make_float2(f.x * sc, f.y * sc));
        }
    }
}

// Fused CSR-build + gather + GEMM: one block (8 waves, 512 thr) per 50-node bin.
// 1000 blocks, 4 blocks/CU wave cap -> all co-resident, balanced makespan.
template <bool PRESCALED>
__global__ __launch_bounds__(512, 8) void k_gcn(
    const unsigned int* __restrict__ rec, const unsigned short* __restrict__ offld,
    const float* __restrict__ ci, const __half* __restrict__ sfeat,
    const float* __restrict__ feat,
    const float* __restrict__ W, const float* __restrict__ b,
    float* __restrict__ out) {
    __shared__ int   colb[EMAX];        // 9.6 KB reordered local col (src ids)
    __shared__ float hl[NPB_D * HS];    // 10.4 KB
    __shared__ float Wl[D * HS];        // 10.0 KB
    __shared__ float bl[D];
    __shared__ int   ideg[NPB_D];
    __shared__ int   off[NPB_D];
    __shared__ int   cur[NPB_D];
    __shared__ int   runoff[PB + 1];
    __shared__ int   runpos[PB];
    __shared__ int   wsum[8], wexcl[8];
    int tid = threadIdx.x, bin = blockIdx.x;
    int wave = tid >> 6, lane = tid & 63;

    for (int i = tid; i < D * D; i += 512) Wl[(i / D) * HS + (i % D)] = W[i];
    if (tid < D) bl[tid] = b[tid];
    if (tid < NPB_D) { ideg[tid] = 0; cur[tid] = 0; }

    // ---- run table + wave-shuffle scan of run lengths ----
    int rlen = 0;
    if (tid < PB) {
        int o0 = offld[tid * (NBIN_D + 1) + bin];
        int o1 = offld[tid * (NBIN_D + 1) + bin + 1];
        rlen = o1 - o0;
        runpos[tid] = tid * EPB + o0;
    }
    int incl = rlen;
    #pragma unroll
    for (int o = 1; o < 64; o <<= 1) {
        int u = __shfl_up(incl, o);
        if (lane >= o) incl += u;
    }
    if (lane == 63) wsum[wave] = incl;
    __syncthreads();
    if (tid < 8) {
        int v = wsum[tid];
        int ic = v;
        #pragma unroll
        for (int o = 1; o < 8; o <<= 1) {
            int u = __shfl_up(ic, o);
            if (lane >= o) ic += u;
        }
        wexcl[tid] = ic - v;
        if (tid == 7) runoff[PB] = ic;
    }
    __syncthreads();
    if (tid < PB) runoff[tid] = wexcl[wave] + incl - rlen;
    __syncthreads();
    int cnt = runoff[PB];
    if (cnt > EMAX) cnt = EMAX;         // unreachable; guards LDS OOB

    // ---- Phase A: gather runs into regs (binary search), histogram, scan, reorder ----
    unsigned int rr[5];
    #pragma unroll
    for (int k = 0; k < 5; ++k) {
        int j = tid + k * 512;
        rr[k] = 0xFFFFFFFFu;
        if (j < cnt) {
            int lo = 0, hi = PB - 1;
            while (lo < hi) {
                int mid = (lo + hi + 1) >> 1;
                if (runoff[mid] <= j) lo = mid; else hi = mid - 1;
            }
            unsigned int r = rec[runpos[lo] + (j - runoff[lo])];
            rr[k] = r;
            atomicAdd(&ideg[r & 63], 1);
        }
    }
    __syncthreads();
    if (tid < NPB_D) {
        int v = ideg[tid];
        int ic = v;
        #pragma unroll
        for (int o = 1; o < 64; o <<= 1) {
            int u = __shfl_up(ic, o);
            if (tid >= o) ic += u;
        }
        off[tid] = ic - v;
    }
    __syncthreads();
    #pragma unroll
    for (int k = 0; k < 5; ++k) {
        if (rr[k] != 0xFFFFFFFFu) {
            int dl = rr[k] & 63;
            int p = atomicAdd(&cur[dl], 1);
            colb[off[dl] + p] = (int)(rr[k] >> 6);
        }
    }
    __syncthreads();

    // ---- Phase B: float4-lane gather; node nl = q*8 + wave (wave-uniform bound) ----
    int eslot = lane / 12;              // 0..5 (slot 5 inactive)
    int d4 = lane - eslot * 12;         // 0..11
    bool lane_ok = (lane < 60);
    const float4* feat4 = (const float4*)feat;
    const uint2* sf = (const uint2*)sfeat;   // 8B = 4 halves per unit, 12/row

    for (int q = 0; q < 7; ++q) {
        int nl = q * 8 + wave;
        if (nl >= NPB_D) break;         // wave-uniform
        int n = bin * NPB_D + nl;
        int cb = off[nl];
        int deg = ideg[nl];

        float4 acc = make_float4(0.0f, 0.0f, 0.0f, 0.0f);
        for (int c0 = 0; c0 < deg; c0 += 60) {
            int jn = min(60, deg - c0);
            int colv = (lane < jn) ? colb[cb + c0 + lane] : 0;
            float civ = 0.0f;
            if (!PRESCALED) civ = (lane < jn) ? ci[colv] : 0.0f;
            for (int i = 0; i < jn; i += 5) {
                int ei = i + eslot;
                // shfls unconditional (full exec) — masked-source bpermute is undefined (R12 bug)
                int s = __shfl(colv, ei);
                float c = PRESCALED ? 0.0f : __shfl(civ, ei);
                if (lane_ok && ei < jn) {
                    if (PRESCALED) {
                        uint2 u = sf[(size_t)s * 12 + d4];
                        __half2 ha = *reinterpret_cast<__half2*>(&u.x);
                        __half2 hb = *reinterpret_cast<__half2*>(&u.y);
                        float2 fa = __half22float2(ha);
                        float2 fb = __half22float2(hb);
                        acc.x += fa.x; acc.y += fa.y; acc.z += fb.x; acc.w += fb.y;
                    } else {
                        float4 f = feat4[(size_t)s * 12 + d4];
                        acc.x = fmaf(f.x, c, acc.x);
                        acc.y = fmaf(f.y, c, acc.y);
                        acc.z = fmaf(f.z, c, acc.z);
                        acc.w = fmaf(f.w, c, acc.w);
                    }
                }
            }
        }
        // reduce 5 edge slots onto lanes 0..11 (temps BEFORE update: no aliasing)
        {
            float x1 = __shfl(acc.x, lane + 12), x2 = __shfl(acc.x, lane + 24);
            float x3 = __shfl(acc.x, lane + 36), x4 = __shfl(acc.x, lane + 48);
            float y1 = __shfl(acc.y, lane + 12), y2 = __shfl(acc.y, lane + 24);
            float y3 = __shfl(acc.y, lane + 36), y4 = __shfl(acc.y, lane + 48);
            float z1 = __shfl(acc.z, lane + 12), z2 = __shfl(acc.z, lane + 24);
            float z3 = __shfl(acc.z, lane + 36), z4 = __shfl(acc.z, lane + 48);
            float w1 = __shfl(acc.w, lane + 12), w2 = __shfl(acc.w, lane + 24);
            float w3 = __shfl(acc.w, lane + 36), w4 = __shfl(acc.w, lane + 48);
            acc.x += (x1 + x2) + (x3 + x4);
            acc.y += (y1 + y2) + (y3 + y4);
            acc.z += (z1 + z2) + (z3 + z4);
            acc.w += (w1 + w2) + (w3 + w4);
        }
        if (lane < 12) {
            float4 res;
            if (deg > 0) {
                float cj = rsqrtf((float)deg);
                res = make_float4(acc.x * cj, acc.y * cj, acc.z * cj, acc.w * cj);
            } else {
                res = feat4[(size_t)n * 12 + d4];
            }
            *(float4*)(hl + nl * HS + d4 * 4) = res;
        }
    }
    __syncthreads();

    // ---- Phase C: out = relu(h @ W^T + b), b128 LDS reads; 2 node-halves ----
    #pragma unroll
    for (int half = 0; half < 2; ++half) {
        int nl = (tid >> 4) + half * 32;
        int c = tid & 15;               // od = c, c+16, c+32
        if (nl < NPB_D) {
            int n = bin * NPB_D + nl;
            float a0 = bl[c], a1 = bl[c + 16], a2 = bl[c + 32];
            #pragma unroll
            for (int k4 = 0; k4 < 12; ++k4) {
                float4 hv = *(const float4*)(hl + nl * HS + k4 * 4);
                float4 w0 = *(const float4*)(Wl + c * HS + k4 * 4);
                float4 w1 = *(const float4*)(Wl + (c + 16) * HS + k4 * 4);
                float4 w2 = *(const float4*)(Wl + (c + 32) * HS + k4 * 4);
                a0 = fmaf(hv.x, w0.x, a0); a0 = fmaf(hv.y, w0.y, a0);
                a0 = fmaf(hv.z, w0.z, a0); a0 = fmaf(hv.w, w0.w, a0);
                a1 = fmaf(hv.x, w1.x, a1); a1 = fmaf(hv.y, w1.y, a1);
                a1 = fmaf(hv.z, w1.z, a1); a1 = fmaf(hv.w, w1.w, a1);
                a2 = fmaf(hv.x, w2.x, a2); a2 = fmaf(hv.y, w2.y, a2);
                a2 = fmaf(hv.z, w2.z, a2); a2 = fmaf(hv.w, w2.w, a2);
            }
            float* op = out + (size_t)n * D;
            op[c]      = fmaxf(a0, 0.0f);
            op[c + 16] = fmaxf(a1, 0.0f);
            op[c + 32] = fmaxf(a2, 0.0f);
        }
    }
}

extern "C" void kernel_launch(void* const* d_in, const int* in_sizes, int n_in,
                              void* d_out, int out_size, void* d_ws, size_t ws_size,
                              hipStream_t stream) {
    const float* feat = (const float*)d_in[0];
    const int*   src  = (const int*)d_in[1];
    const int*   dst  = (const int*)d_in[2];
    const float* W    = (const float*)d_in[3];
    const float* b    = (const float*)d_in[4];
    float* out = (float*)d_out;

    char* ws = (char*)d_ws;
    unsigned int*   rec   = (unsigned int*)(ws + RECD_OFF);
    unsigned char*  srcb  = (unsigned char*)(ws + SRCB_OFF);
    unsigned short* offld = (unsigned short*)(ws + OFFLD_OFF);
    unsigned short* offls = (unsigned short*)(ws + OFFLS_OFF);
    float*          ci    = (float*)(ws + CI_OFF);
    __half*         sfeat = (__half*)(ws + SFEAT_OFF);

    const bool prescale = (ws_size >= (size_t)SFEAT_END);

    k_prep<<<PB, 1024, 0, stream>>>(src, dst, rec, srcb, offld, offls);
    k_ci<<<NBIN_S, 512, 0, stream>>>(srcb, offls, feat, ci, sfeat, prescale ? 1 : 0);
    if (prescale)
        k_gcn<true><<<NBIN_D, 512, 0, stream>>>(rec, offld, ci, sfeat, feat, W, b, out);
    else
        k_gcn<false><<<NBIN_D, 512, 0, stream>>>(rec, offld, ci, sfeat, feat, W, b, out);
}

// Round 17
// 140.685 us; speedup vs baseline: 1.6847x; 1.0067x over previous
//
#include <hip/hip_runtime.h>
#include <hip/hip_fp16.h>

#define N_NODES 50000
#define N_EDGES 1600000
#define D 48

#define EPB 8192            // edges per prep block
#define PB  196             // ceil(N_EDGES/EPB)
#define NPB_D 50            // dst-bin size: 1000 bins exactly, balanced 4/CU grid
#define NBIN_D 1000
#define NPB_S 256
#define NBIN_S 196          // ceil(50000/256)

#define EMAX 2400           // per-dst-bin edge cap (mean 1600, sigma ~40 -> 20 sigma)
#define HS 52               // h/W LDS stride (16B-aligned, bank-spread; proven R10)

// ---------- workspace layout (bytes) ----------
#define RECD_OFF  0          // u32[PB*EPB] block-major: (src<<6)|dlocal
#define SRCB_OFF  6422528    // u8 [PB*EPB] block-major: src&255
#define OFFLD_OFF 8028160    // u16[PB][NBIN_D+1]
#define OFFLS_OFF 8420552    // u16[PB][NBIN_S+1]
#define CI_OFF    8497776    // f32[50000]
#define SFEAT_OFF 8697776    // f16[50000*48] prescaled (optional)
#define SFEAT_END 13497776

// One kernel = count + scan + scatter, all block-local. Coalesced output only.
__global__ __launch_bounds__(1024) void k_prep(const int* __restrict__ src,
                                               const int* __restrict__ dst,
                                               unsigned int* __restrict__ rec,
                                               unsigned char* __restrict__ srcb,
                                               unsigned short* __restrict__ offld,
                                               unsigned short* __restrict__ offls) {
    __shared__ int cd[NBIN_D];                  // histogram, then cursor
    __shared__ int cs[NBIN_S];
    __shared__ int wsum[16], wexcl[16];
    __shared__ int wsum2[4], wexcl2[4];
    __shared__ alignas(16) unsigned int  bufd[EPB];
    __shared__ alignas(16) unsigned char bufs[EPB];
    int tid = threadIdx.x, p = blockIdx.x;
    int wave = tid >> 6, lane = tid & 63;
    int base = p * EPB;

    int sv[8], dv[8];
    bool ok[8];
    #pragma unroll
    for (int k = 0; k < 8; ++k) {
        int e = base + tid + k * 1024;
        ok[k] = (e < N_EDGES);
        sv[k] = ok[k] ? src[e] : 0;
        dv[k] = ok[k] ? dst[e] : 0;
    }

    for (int i = tid; i < NBIN_D; i += 1024) cd[i] = 0;
    for (int i = tid; i < NBIN_S; i += 1024) cs[i] = 0;
    __syncthreads();
    #pragma unroll
    for (int k = 0; k < 8; ++k) {
        if (ok[k]) {
            atomicAdd(&cd[dv[k] / NPB_D], 1);
            atomicAdd(&cs[sv[k] >> 8], 1);
        }
    }
    __syncthreads();

    // wave-shuffle scan over cd (1000 elements, threads 0..999)
    int own = (tid < NBIN_D) ? cd[tid] : 0;
    int incl = own;
    #pragma unroll
    for (int o = 1; o < 64; o <<= 1) {
        int u = __shfl_up(incl, o);
        if (lane >= o) incl += u;
    }
    if (lane == 63) wsum[wave] = incl;
    __syncthreads();
    if (tid < 16) {
        int v = wsum[tid];
        int ic = v;
        #pragma unroll
        for (int o = 1; o < 16; o <<= 1) {
            int u = __shfl_up(ic, o);
            if (lane >= o) ic += u;
        }
        wexcl[tid] = ic - v;
    }
    __syncthreads();
    if (tid < NBIN_D) {
        int gincl = wexcl[wave] + incl;
        int ex = gincl - own;
        offld[p * (NBIN_D + 1) + tid] = (unsigned short)ex;
        cd[tid] = ex;                           // cursor
        if (tid == NBIN_D - 1) offld[p * (NBIN_D + 1) + NBIN_D] = (unsigned short)gincl;
    }

    // wave-shuffle scan over cs (196 elements, threads 0..195)
    int own2 = (tid < NBIN_S) ? cs[tid] : 0;
    int incl2 = own2;
    #pragma unroll
    for (int o = 1; o < 64; o <<= 1) {
        int u = __shfl_up(incl2, o);
        if (lane >= o) incl2 += u;
    }
    if (lane == 63 && wave < 4) wsum2[wave] = incl2;
    __syncthreads();
    if (tid < 4) {
        int v = wsum2[tid];
        int ic = v;
        #pragma unroll
        for (int o = 1; o < 4; o <<= 1) {
            int u = __shfl_up(ic, o);
            if (lane >= o) ic += u;
        }
        wexcl2[tid] = ic - v;
    }
    __syncthreads();
    if (tid < NBIN_S) {
        int gincl2 = wexcl2[wave] + incl2;
        int ex = gincl2 - own2;
        offls[p * (NBIN_S + 1) + tid] = (unsigned short)ex;
        cs[tid] = ex;                           // cursor
        if (tid == NBIN_S - 1) offls[p * (NBIN_S + 1) + NBIN_S] = (unsigned short)gincl2;
    }
    __syncthreads();

    #pragma unroll
    for (int k = 0; k < 8; ++k) {
        if (ok[k]) {
            int s = sv[k], d = dv[k];
            int bin = d / NPB_D;
            int pd = atomicAdd(&cd[bin], 1);
            bufd[pd] = ((unsigned int)s << 6) | (unsigned int)(d - bin * NPB_D);
            int ps = atomicAdd(&cs[s >> 8], 1);
            bufs[ps] = (unsigned char)s;
        }
    }
    __syncthreads();

    // coalesced full-line streams out
    int4* ro = (int4*)(rec + base);
    const int4* bi = (const int4*)bufd;
    for (int i = tid; i < EPB / 4; i += 1024) ro[i] = bi[i];
    unsigned int* so = (unsigned int*)(srcb + base);
    const unsigned int* bs = (const unsigned int*)bufs;
    for (int i = tid; i < EPB / 4; i += 1024) so[i] = bs[i];
}

// one block per src-bin: gather its PB runs, LDS histogram -> ci (+ fp16 sfeat)
__global__ __launch_bounds__(512) void k_ci(const unsigned char* __restrict__ srcb,
                                            const unsigned short* __restrict__ offls,
                                            const float* __restrict__ feat,
                                            float* __restrict__ ci,
                                            __half* __restrict__ sfeat,
                                            int do_scale) {
    __shared__ int cnt[NPB_S];
    __shared__ float cl[NPB_S];
    int tid = threadIdx.x, sb = blockIdx.x;
    for (int i = tid; i < NPB_S; i += 512) cnt[i] = 0;
    __syncthreads();
    int wave = tid >> 6, lane = tid & 63;
    for (int p = wave; p < PB; p += 8) {
        int beg = offls[p * (NBIN_S + 1) + sb];
        int end = offls[p * (NBIN_S + 1) + sb + 1];
        for (int j = beg + lane; j < end; j += 64)
            atomicAdd(&cnt[srcb[p * EPB + j]], 1);
    }
    __syncthreads();
    if (tid < NPB_S) {
        float c = rsqrtf(fmaxf((float)cnt[tid], 1.0f));
        cl[tid] = c;
        int n = sb * NPB_S + tid;
        if (n < N_NODES) ci[n] = c;
    }
    __syncthreads();
    if (do_scale) {
        int nb = sb * NPB_S;
        int lim2 = (min(NPB_S, N_NODES - nb)) * 24;   // half2 units (2 floats each)
        const float2* f2 = (const float2*)feat + (size_t)nb * 24;
        __half2* s2 = (__half2*)sfeat + (size_t)nb * 24;
        for (int i = tid; i < lim2; i += 512) {
            float sc = cl[i / 24];
            float2 f = f2[i];
            s2[i] = __float22half2_rn(make_float2(f.x * sc, f.y * sc));
        }
    }
}

// Fused CSR-build + gather + GEMM: one block (8 waves, 512 thr) per 50-node bin.
// 1000 blocks, 4 blocks/CU wave cap -> all co-resident, balanced makespan.
template <bool PRESCALED>
__global__ __launch_bounds__(512, 8) void k_gcn(
    const unsigned int* __restrict__ rec, const unsigned short* __restrict__ offld,
    const float* __restrict__ ci, const __half* __restrict__ sfeat,
    const float* __restrict__ feat,
    const float* __restrict__ W, const float* __restrict__ b,
    float* __restrict__ out) {
    __shared__ int   colb[EMAX];        // 9.6 KB reordered local col (src ids)
    __shared__ float hl[NPB_D * HS];    // 10.4 KB
    __shared__ float Wl[D * HS];        // 10.0 KB
    __shared__ float bl[D];
    __shared__ int   ideg[NPB_D];
    __shared__ int   off[NPB_D];
    __shared__ int   cur[NPB_D];
    __shared__ int   runoff[PB + 1];
    __shared__ int   runpos[PB];
    __shared__ int   wsum[8], wexcl[8];
    int tid = threadIdx.x, bin = blockIdx.x;
    int wave = tid >> 6, lane = tid & 63;

    for (int i = tid; i < D * D; i += 512) Wl[(i / D) * HS + (i % D)] = W[i];
    if (tid < D) bl[tid] = b[tid];
    if (tid < NPB_D) { ideg[tid] = 0; cur[tid] = 0; }

    // ---- run table + wave-shuffle scan of run lengths ----
    int rlen = 0;
    if (tid < PB) {
        int o0 = offld[tid * (NBIN_D + 1) + bin];
        int o1 = offld[tid * (NBIN_D + 1) + bin + 1];
        rlen = o1 - o0;
        runpos[tid] = tid * EPB + o0;
    }
    int incl = rlen;
    #pragma unroll
    for (int o = 1; o < 64; o <<= 1) {
        int u = __shfl_up(incl, o);
        if (lane >= o) incl += u;
    }
    if (lane == 63) wsum[wave] = incl;
    __syncthreads();
    if (tid < 8) {
        int v = wsum[tid];
        int ic = v;
        #pragma unroll
        for (int o = 1; o < 8; o <<= 1) {
            int u = __shfl_up(ic, o);
            if (lane >= o) ic += u;
        }
        wexcl[tid] = ic - v;
        if (tid == 7) runoff[PB] = ic;
    }
    __syncthreads();
    if (tid < PB) runoff[tid] = wexcl[wave] + incl - rlen;
    __syncthreads();
    int cnt = runoff[PB];
    if (cnt > EMAX) cnt = EMAX;         // unreachable; guards LDS OOB

    // ---- Phase A: gather runs into regs (binary search), histogram, scan, reorder ----
    unsigned int rr[5];
    #pragma unroll
    for (int k = 0; k < 5; ++k) {
        int j = tid + k * 512;
        rr[k] = 0xFFFFFFFFu;
        if (j < cnt) {
            int lo = 0, hi = PB - 1;
            while (lo < hi) {
                int mid = (lo + hi + 1) >> 1;
                if (runoff[mid] <= j) lo = mid; else hi = mid - 1;
            }
            unsigned int r = rec[runpos[lo] + (j - runoff[lo])];
            rr[k] = r;
            atomicAdd(&ideg[r & 63], 1);
        }
    }
    __syncthreads();
    if (tid < NPB_D) {
        int v = ideg[tid];
        int ic = v;
        #pragma unroll
        for (int o = 1; o < 64; o <<= 1) {
            int u = __shfl_up(ic, o);
            if (tid >= o) ic += u;
        }
        off[tid] = ic - v;
    }
    __syncthreads();
    #pragma unroll
    for (int k = 0; k < 5; ++k) {
        if (rr[k] != 0xFFFFFFFFu) {
            int dl = rr[k] & 63;
            int p = atomicAdd(&cur[dl], 1);
            colb[off[dl] + p] = (int)(rr[k] >> 6);
        }
    }
    __syncthreads();

    // ---- Phase B: float4-lane gather; node nl = q*8 + wave (wave-uniform bound) ----
    // Direct per-lane LDS reads replace the shfl broadcast: the 12 lanes of an
    // edge-slot read the SAME colb address (HW broadcast, conflict-free), so no
    // bpermute and no 60-edge staging layer are needed.
    int eslot = lane / 12;              // 0..5 (slot 5 inactive)
    int d4 = lane - eslot * 12;         // 0..11
    bool lane_ok = (lane < 60);
    const float4* feat4 = (const float4*)feat;
    const uint2* sf = (const uint2*)sfeat;   // 8B = 4 halves per unit, 12/row

    for (int q = 0; q < 7; ++q) {
        int nl = q * 8 + wave;
        if (nl >= NPB_D) break;         // wave-uniform
        int n = bin * NPB_D + nl;
        int cb = off[nl];
        int deg = ideg[nl];

        float4 acc = make_float4(0.0f, 0.0f, 0.0f, 0.0f);
        for (int i0 = 0; i0 < deg; i0 += 5) {
            int ei = i0 + eslot;
            bool act = lane_ok && (ei < deg);
            int s = act ? colb[cb + ei] : 0;
            if (act) {
                if (PRESCALED) {
                    uint2 u = sf[(size_t)s * 12 + d4];
                    __half2 ha = *reinterpret_cast<__half2*>(&u.x);
                    __half2 hb = *reinterpret_cast<__half2*>(&u.y);
                    float2 fa = __half22float2(ha);
                    float2 fb = __half22float2(hb);
                    acc.x += fa.x; acc.y += fa.y; acc.z += fb.x; acc.w += fb.y;
                } else {
                    float c = ci[s];    // 12 lanes same address: single line
                    float4 f = feat4[(size_t)s * 12 + d4];
                    acc.x = fmaf(f.x, c, acc.x);
                    acc.y = fmaf(f.y, c, acc.y);
                    acc.z = fmaf(f.z, c, acc.z);
                    acc.w = fmaf(f.w, c, acc.w);
                }
            }
        }
        // reduce 5 edge slots onto lanes 0..11 (temps BEFORE update: no aliasing)
        {
            float x1 = __shfl(acc.x, lane + 12), x2 = __shfl(acc.x, lane + 24);
            float x3 = __shfl(acc.x, lane + 36), x4 = __shfl(acc.x, lane + 48);
            float y1 = __shfl(acc.y, lane + 12), y2 = __shfl(acc.y, lane + 24);
            float y3 = __shfl(acc.y, lane + 36), y4 = __shfl(acc.y, lane + 48);
            float z1 = __shfl(acc.z, lane + 12), z2 = __shfl(acc.z, lane + 24);
            float z3 = __shfl(acc.z, lane + 36), z4 = __shfl(acc.z, lane + 48);
            float w1 = __shfl(acc.w, lane + 12), w2 = __shfl(acc.w, lane + 24);
            float w3 = __shfl(acc.w, lane + 36), w4 = __shfl(acc.w, lane + 48);
            acc.x += (x1 + x2) + (x3 + x4);
            acc.y += (y1 + y2) + (y3 + y4);
            acc.z += (z1 + z2) + (z3 + z4);
            acc.w += (w1 + w2) + (w3 + w4);
        }
        if (lane < 12) {
            float4 res;
            if (deg > 0) {
                float cj = rsqrtf((float)deg);
                res = make_float4(acc.x * cj, acc.y * cj, acc.z * cj, acc.w * cj);
            } else {
                res = feat4[(size_t)n * 12 + d4];
            }
            *(float4*)(hl + nl * HS + d4 * 4) = res;
        }
    }
    __syncthreads();

    // ---- Phase C: out = relu(h @ W^T + b), b128 LDS reads; 2 node-halves ----
    #pragma unroll
    for (int half = 0; half < 2; ++half) {
        int nl = (tid >> 4) + half * 32;
        int c = tid & 15;               // od = c, c+16, c+32
        if (nl < NPB_D) {
            int n = bin * NPB_D + nl;
            float a0 = bl[c], a1 = bl[c + 16], a2 = bl[c + 32];
            #pragma unroll
            for (int k4 = 0; k4 < 12; ++k4) {
                float4 hv = *(const float4*)(hl + nl * HS + k4 * 4);
                float4 w0 = *(const float4*)(Wl + c * HS + k4 * 4);
                float4 w1 = *(const float4*)(Wl + (c + 16) * HS + k4 * 4);
                float4 w2 = *(const float4*)(Wl + (c + 32) * HS + k4 * 4);
                a0 = fmaf(hv.x, w0.x, a0); a0 = fmaf(hv.y, w0.y, a0);
                a0 = fmaf(hv.z, w0.z, a0); a0 = fmaf(hv.w, w0.w, a0);
                a1 = fmaf(hv.x, w1.x, a1); a1 = fmaf(hv.y, w1.y, a1);
                a1 = fmaf(hv.z, w1.z, a1); a1 = fmaf(hv.w, w1.w, a1);
                a2 = fmaf(hv.x, w2.x, a2); a2 = fmaf(hv.y, w2.y, a2);
                a2 = fmaf(hv.z, w2.z, a2); a2 = fmaf(hv.w, w2.w, a2);
            }
            float* op = out + (size_t)n * D;
            op[c]      = fmaxf(a0, 0.0f);
            op[c + 16] = fmaxf(a1, 0.0f);
            op[c + 32] = fmaxf(a2, 0.0f);
        }
    }
}

extern "C" void kernel_launch(void* const* d_in, const int* in_sizes, int n_in,
                              void* d_out, int out_size, void* d_ws, size_t ws_size,
                              hipStream_t stream) {
    const float* feat = (const float*)d_in[0];
    const int*   src  = (const int*)d_in[1];
    const int*   dst  = (const int*)d_in[2];
    const float* W    = (const float*)d_in[3];
    const float* b    = (const float*)d_in[4];
    float* out = (float*)d_out;

    char* ws = (char*)d_ws;
    unsigned int*   rec   = (unsigned int*)(ws + RECD_OFF);
    unsigned char*  srcb  = (unsigned char*)(ws + SRCB_OFF);
    unsigned short* offld = (unsigned short*)(ws + OFFLD_OFF);
    unsigned short* offls = (unsigned short*)(ws + OFFLS_OFF);
    float*          ci    = (float*)(ws + CI_OFF);
    __half*         sfeat = (__half*)(ws + SFEAT_OFF);

    const bool prescale = (ws_size >= (size_t)SFEAT_END);

    k_prep<<<PB, 1024, 0, stream>>>(src, dst, rec, srcb, offld, offls);
    k_ci<<<NBIN_S, 512, 0, stream>>>(srcb, offls, feat, ci, sfeat, prescale ? 1 : 0);
    if (prescale)
        k_gcn<true><<<NBIN_D, 512, 0, stream>>>(rec, offld, ci, sfeat, feat, W, b, out);
    else
        k_gcn<false><<<NBIN_D, 512, 0, stream>>>(rec, offld, ci, sfeat, feat, W, b, out);
}